// Round 4
// baseline (739.077 us; speedup 1.0000x reference)
//
#include <hip/hip_runtime.h>

#define BB 4096
#define TT 256
#define FF 32
#define HH 6

#define DPP_XOR1 0xB1   // quad_perm(1,0,3,2)
#define DPP_XOR2 0x4E   // quad_perm(2,3,0,1)
#define DPP_XOR3 0x1B   // quad_perm(3,2,1,0)
#define DPP_HALF 0x141  // row_half_mirror = xor 7 within 8-lane half-rows

__device__ __forceinline__ float fast_rcp(float x) { return __builtin_amdgcn_rcpf(x); }
__device__ __forceinline__ float sigmoidf(float x) { return fast_rcp(1.0f + __expf(-x)); }

template <int CTRL>
__device__ __forceinline__ float dppf(float x) {
    return __int_as_float(__builtin_amdgcn_update_dpp(
        0, __float_as_int(x), CTRL, 0xF, 0xF, true));
}
__device__ __forceinline__ float dpp_xor4(float x) {
    return dppf<DPP_HALF>(dppf<DPP_XOR3>(x));
}

// K1: per-(b,t) thread. Online softmax-attention + input projection:
//   s = x@Wa + ba;  e = exp(s) (no max-sub, |s| small);  sum = Σe
//   z = bl + (Σ_f e[f]·x[f]·Wl[f,:]) / sum
// Output layout: [b][t][j=0..5][gate 0..3] fp32 (24 floats / item).
__global__ __launch_bounds__(256, 4) void k_attn_xz(
    const float* __restrict__ x, const float* __restrict__ Wa, const float* __restrict__ ba,
    const float* __restrict__ Wl, const float* __restrict__ bl, float* __restrict__ xz)
{
    const int id = blockIdx.x * 256 + threadIdx.x;   // id = b*TT + t
    const float* xp = x + (size_t)id * FF;

    // Phase A: scores (xv + s live; Wa rows are wave-uniform -> scalar loads)
    float xv[FF];
#pragma unroll
    for (int q = 0; q < FF / 4; ++q) {
        float4 v = *(const float4*)(xp + q * 4);
        xv[q*4+0] = v.x; xv[q*4+1] = v.y; xv[q*4+2] = v.z; xv[q*4+3] = v.w;
    }
    float s[FF];
#pragma unroll
    for (int f2 = 0; f2 < FF; ++f2) s[f2] = ba[f2];
#pragma unroll
    for (int f = 0; f < FF; ++f) {
        const float xf = xv[f];
#pragma unroll
        for (int f2 = 0; f2 < FF; ++f2) s[f2] = fmaf(xf, Wa[f * FF + f2], s[f2]);
    }

    // Phase B: online accumulation over f (xv re-read from L1, 4 at a time)
    float acc[4 * HH];
#pragma unroll
    for (int g = 0; g < 4 * HH; ++g) acc[g] = 0.0f;
    float sum = 0.0f;
#pragma unroll
    for (int q = 0; q < FF / 4; ++q) {
        const float4 xq = *(const float4*)(xp + q * 4);
#pragma unroll
        for (int k = 0; k < 4; ++k) {
            const int f = q * 4 + k;
            const float e = __expf(s[f]);
            sum += e;
            const float xk = (k == 0) ? xq.x : (k == 1) ? xq.y : (k == 2) ? xq.z : xq.w;
            const float w = e * xk;
            const float* wl = Wl + f * (4 * HH);
#pragma unroll
            for (int g = 0; g < 4 * HH; ++g) acc[g] = fmaf(w, wl[g], acc[g]);
        }
    }
    const float r = fast_rcp(sum);

    float* op = xz + (size_t)id * 24;
#pragma unroll
    for (int jp = 0; jp < HH; ++jp) {
        float4 v;
        v.x = fmaf(acc[0 * HH + jp], r, bl[0 * HH + jp]);   // i
        v.y = fmaf(acc[1 * HH + jp], r, bl[1 * HH + jp]);   // f
        v.z = fmaf(acc[2 * HH + jp], r, bl[2 * HH + jp]);   // g pre-act
        v.w = fmaf(acc[3 * HH + jp], r, bl[3 * HH + jp]);   // o
        *(float4*)(op + jp * 4) = v;
    }
}

// K2: LSTM scan. 8 lanes/batch, DPP cross-lane, W10 in LDS, 12-step-deep prefetch.
// launch_bounds(64,1): only 2 waves/CU resident anyway -> give the pipeline all 512 VGPRs.
__global__ __launch_bounds__(64, 1) void k_scan(
    const float* __restrict__ xz, const float* __restrict__ Ul,
    const float* __restrict__ W10, const float* __restrict__ b10,
    const float* __restrict__ Wo, const float* __restrict__ bo,
    float* __restrict__ out)
{
    const int lane = threadIdx.x;
    const int j = lane & 7;
    const int b = blockIdx.x * 8 + (lane >> 3);
    const bool real = (j < HH);
    const int jc = real ? j : 0;

    __shared__ __align__(16) float w10s[TT * HH * 10 + 64];  // +junk row for t=256 prefetch
    {
        const float2* src = (const float2*)W10;
        float2* dst = (float2*)w10s;
        for (int i = lane; i < (TT * HH * 10) / 2; i += 64) dst[i] = src[i];
    }
    __syncthreads();

    // Recurrent coeffs in xor-ladder order: hl[m] corresponds to unit (j^m).
    float Ui[8], Uf[8], Ug[8], Uo[8];
#pragma unroll
    for (int m = 0; m < 8; ++m) {
        const int src = j ^ m;
        const bool ok = real && (src < HH);
        const float* row = Ul + (ok ? src : 0) * 24;
        Ui[m] = ok ? row[0  + j] : 0.0f;
        Uf[m] = ok ? row[6  + j] : 0.0f;
        Ug[m] = ok ? row[12 + j] : 0.0f;
        Uo[m] = ok ? row[18 + j] : 0.0f;
    }

    float hl[8];           // holds ovec = ov*ec of unit (j^m); true h = ovec * r2
    float r2 = 1.0f;       // rcp of last c-softmax sum (uniform in group)
    float c = 0.0f;
    float y[10];
#pragma unroll
    for (int m = 0; m < 8; ++m) hl[m] = 0.0f;
#pragma unroll
    for (int p = 0; p < 10; ++p) y[p] = 0.0f;

    float2 wrow[5];
#pragma unroll
    for (int q = 0; q < 5; ++q) wrow[q] = *(const float2*)(w10s + jc * 10 + q * 2);

    const float* xb = xz + (size_t)b * (TT * 24) + j * 4;

    auto step = [&](const float4 z4, const int t) {
        // z = z4 + (sum_m hl[m]*U[m]) * r2   (split into two chains of 4)
        float di0 = hl[0]*Ui[0], di1 = hl[4]*Ui[4];
        float df0 = hl[0]*Uf[0], df1 = hl[4]*Uf[4];
        float dg0 = hl[0]*Ug[0], dg1 = hl[4]*Ug[4];
        float dq0 = hl[0]*Uo[0], dq1 = hl[4]*Uo[4];
#pragma unroll
        for (int m = 1; m < 4; ++m) {
            di0 = fmaf(hl[m], Ui[m], di0); di1 = fmaf(hl[m+4], Ui[m+4], di1);
            df0 = fmaf(hl[m], Uf[m], df0); df1 = fmaf(hl[m+4], Uf[m+4], df1);
            dg0 = fmaf(hl[m], Ug[m], dg0); dg1 = fmaf(hl[m+4], Ug[m+4], dg1);
            dq0 = fmaf(hl[m], Uo[m], dq0); dq1 = fmaf(hl[m+4], Uo[m+4], dq1);
        }
        const float zi = fmaf(di0 + di1, r2, z4.x);
        const float zf = fmaf(df0 + df1, r2, z4.y);
        const float zg = fmaf(dg0 + dg1, r2, z4.z);
        const float zo = fmaf(dq0 + dq1, r2, z4.w);

        const float iv = sigmoidf(zi);
        const float fv = sigmoidf(zf);
        const float ov = sigmoidf(zo);

        // g-softmax without max-subtraction (|zg| small; pads masked to 0)
        const float eg = real ? __expf(zg) : 0.0f;
        float s1 = eg;
        s1 += dppf<DPP_XOR1>(s1);
        s1 += dppf<DPP_XOR2>(s1);
        s1 += dpp_xor4(s1);
        c = fmaf(fv, c, (iv * eg) * fast_rcp(s1));

        // c-softmax (keep max for safety)
        const float cmsk = real ? c : -1e30f;
        float m2 = fmaxf(cmsk, dppf<DPP_XOR1>(cmsk));
        m2 = fmaxf(m2, dppf<DPP_XOR2>(m2));
        m2 = fmaxf(m2, dpp_xor4(m2));
        const float ec = real ? __expf(c - m2) : 0.0f;
        float s2 = ec;
        s2 += dppf<DPP_XOR1>(s2);
        s2 += dppf<DPP_XOR2>(s2);
        s2 += dpp_xor4(s2);

        // broadcast ovec = ov*ec (r2 applied at next matvec; rcp hidden under ladder)
        const float ovec = ov * ec;
        hl[0] = ovec;
        hl[1] = dppf<DPP_XOR1>(ovec);
        hl[2] = dppf<DPP_XOR2>(ovec);
        hl[3] = dppf<DPP_XOR3>(ovec);
        const float h7 = dppf<DPP_HALF>(ovec);
        hl[7] = h7;
        hl[6] = dppf<DPP_XOR1>(h7);
        hl[5] = dppf<DPP_XOR2>(h7);
        hl[4] = dppf<DPP_XOR3>(h7);
        r2 = fast_rcp(s2);
        const float hn = ovec * r2;   // actual h for this lane's unit (pads: 0)

        // prefetch next W10 row from LDS, consume current
        float2 wn[5];
        const int rn = ((t + 1) * HH + jc) * 10;
#pragma unroll
        for (int q = 0; q < 5; ++q) wn[q] = *(const float2*)(w10s + rn + q * 2);
#pragma unroll
        for (int q = 0; q < 5; ++q) {
            y[2*q]   = fmaf(hn, wrow[q].x, y[2*q]);
            y[2*q+1] = fmaf(hn, wrow[q].y, y[2*q+1]);
        }
#pragma unroll
        for (int q = 0; q < 5; ++q) wrow[q] = wn[q];
    };

    float4 A[4], B[4], C[4], D[4];
    const float* xp = xb;

#define LDBLK(Bf, dt0)                                                  \
    { _Pragma("unroll") for (int q = 0; q < 4; ++q)                     \
        Bf[q] = *(const float4*)(xp + (dt0 + q) * 24); }

    LDBLK(A, 0); LDBLK(B, 4); LDBLK(C, 8);

#pragma unroll 1
    for (int it = 0; it < 16; ++it) {
        const int t0 = it * 16;
        LDBLK(D, 12);
        step(A[0], t0 + 0);  step(A[1], t0 + 1);  step(A[2], t0 + 2);  step(A[3], t0 + 3);
        LDBLK(A, 16);   // next iter's A (last iter: dead load into valid ws memory)
        step(B[0], t0 + 4);  step(B[1], t0 + 5);  step(B[2], t0 + 6);  step(B[3], t0 + 7);
        LDBLK(B, 20);
        step(C[0], t0 + 8);  step(C[1], t0 + 9);  step(C[2], t0 + 10); step(C[3], t0 + 11);
        LDBLK(C, 24);
        step(D[0], t0 + 12); step(D[1], t0 + 13); step(D[2], t0 + 14); step(D[3], t0 + 15);
        xp += 16 * 24;
    }
#undef LDBLK

    // reduce y across the 8-lane group (pads contributed 0)
#pragma unroll
    for (int p = 0; p < 10; ++p) {
        float v = y[p];
        v += dppf<DPP_XOR1>(v);
        v += dppf<DPP_XOR2>(v);
        v += dpp_xor4(v);
        y[p] = v;
    }

    // fused dense(8): lane j emits output column j
    float o8 = bo[j];
#pragma unroll
    for (int p = 0; p < 10; ++p) o8 = fmaf(y[p] + b10[p], Wo[p * 8 + j], o8);
    out[(size_t)b * 8 + j] = o8;
}

extern "C" void kernel_launch(void* const* d_in, const int* in_sizes, int n_in,
                              void* d_out, int out_size, void* d_ws, size_t ws_size,
                              hipStream_t stream) {
    const float* x   = (const float*)d_in[0];
    const float* Wa  = (const float*)d_in[1];
    const float* ba  = (const float*)d_in[2];
    const float* Wl  = (const float*)d_in[3];
    const float* Ul  = (const float*)d_in[4];
    const float* bl  = (const float*)d_in[5];
    const float* W10 = (const float*)d_in[6];
    const float* b10 = (const float*)d_in[7];
    const float* Wo  = (const float*)d_in[8];
    const float* bo  = (const float*)d_in[9];
    float* out = (float*)d_out;
    float* xz  = (float*)d_ws;   // BB*TT*24*4 = 96 MiB (+ slack for tail prefetch)

    hipLaunchKernelGGL(k_attn_xz, dim3(BB * TT / 256), dim3(256), 0, stream,
                       x, Wa, ba, Wl, bl, xz);
    hipLaunchKernelGGL(k_scan, dim3(BB / 8), dim3(64), 0, stream,
                       xz, Ul, W10, b10, Wo, bo, out);
}

// Round 5
// 191.704 us; speedup vs baseline: 3.8553x; 3.8553x over previous
//
#include <hip/hip_runtime.h>

#define BB 4096
#define TT 256
#define FF 32
#define HH 6

#define DPP_XOR1 0xB1   // quad_perm(1,0,3,2)
#define DPP_XOR2 0x4E   // quad_perm(2,3,0,1)
#define DPP_XOR3 0x1B   // quad_perm(3,2,1,0)
#define DPP_HALF 0x141  // row_half_mirror = xor 7 within 8-lane half-rows

__device__ __forceinline__ float fast_rcp(float x) { return __builtin_amdgcn_rcpf(x); }
__device__ __forceinline__ float sigmoidf(float x) { return fast_rcp(1.0f + __expf(-x)); }

template <int CTRL>
__device__ __forceinline__ float dppf(float x) {
    return __int_as_float(__builtin_amdgcn_update_dpp(
        0, __float_as_int(x), CTRL, 0xF, 0xF, true));
}
__device__ __forceinline__ float dpp_xor4(float x) {
    return dppf<DPP_HALF>(dppf<DPP_XOR3>(x));
}

// K1 (R3 version, known-good): per-(b,t) thread: attention softmax over F,
// feat = x*w, z = feat@Wl + bl.
// Output layout: [b][t][j=0..5][gate 0..3] fp32 (24 floats / item).
__global__ __launch_bounds__(256, 4) void k_attn_xz(
    const float* __restrict__ x, const float* __restrict__ Wa, const float* __restrict__ ba,
    const float* __restrict__ Wl, const float* __restrict__ bl, float* __restrict__ xz)
{
    const int id = blockIdx.x * 256 + threadIdx.x;   // id = b*TT + t
    const float* xp = x + (size_t)id * FF;

    float xv[FF];
#pragma unroll
    for (int q = 0; q < FF / 4; ++q) {
        float4 v = *(const float4*)(xp + q * 4);
        xv[q*4+0] = v.x; xv[q*4+1] = v.y; xv[q*4+2] = v.z; xv[q*4+3] = v.w;
    }

    float s[FF];
#pragma unroll
    for (int f2 = 0; f2 < FF; ++f2) s[f2] = ba[f2];
#pragma unroll
    for (int f = 0; f < FF; ++f) {
        const float xf = xv[f];
#pragma unroll
        for (int f2 = 0; f2 < FF; ++f2) s[f2] = fmaf(xf, Wa[f * FF + f2], s[f2]);
    }

    float mx = s[0];
#pragma unroll
    for (int f = 1; f < FF; ++f) mx = fmaxf(mx, s[f]);
    float sum = 0.0f;
#pragma unroll
    for (int f = 0; f < FF; ++f) { s[f] = __expf(s[f] - mx); sum += s[f]; }
    const float r = fast_rcp(sum);

    float acc[4 * HH];
#pragma unroll
    for (int g = 0; g < 4 * HH; ++g) acc[g] = bl[g];
#pragma unroll
    for (int f = 0; f < FF; ++f) {
        const float ff = xv[f] * s[f] * r;
#pragma unroll
        for (int g = 0; g < 4 * HH; ++g) acc[g] = fmaf(ff, Wl[f * (4 * HH) + g], acc[g]);
    }

    float* op = xz + (size_t)id * 24;
#pragma unroll
    for (int jp = 0; jp < HH; ++jp) {
        float4 v;
        v.x = acc[0 * HH + jp];   // i
        v.y = acc[1 * HH + jp];   // f
        v.z = acc[2 * HH + jp];   // g pre-act
        v.w = acc[3 * HH + jp];   // o
        *(float4*)(op + jp * 4) = v;
    }
}

// K2: LSTM scan. 8 lanes/batch, DPP cross-lane, W10 in LDS, 12-step-deep prefetch.
// launch_bounds(64,1): only 2 waves/CU resident anyway -> give the pipeline all 512 VGPRs.
__global__ __launch_bounds__(64, 1) void k_scan(
    const float* __restrict__ xz, const float* __restrict__ Ul,
    const float* __restrict__ W10, const float* __restrict__ b10,
    const float* __restrict__ Wo, const float* __restrict__ bo,
    float* __restrict__ out)
{
    const int lane = threadIdx.x;
    const int j = lane & 7;
    const int b = blockIdx.x * 8 + (lane >> 3);
    const bool real = (j < HH);
    const int jc = real ? j : 0;

    __shared__ __align__(16) float w10s[TT * HH * 10 + 64];  // +junk row for t=256 prefetch
    {
        const float2* src = (const float2*)W10;
        float2* dst = (float2*)w10s;
        for (int i = lane; i < (TT * HH * 10) / 2; i += 64) dst[i] = src[i];
    }
    __syncthreads();

    // Recurrent coeffs in xor-ladder order: hl[m] corresponds to unit (j^m).
    float Ui[8], Uf[8], Ug[8], Uo[8];
#pragma unroll
    for (int m = 0; m < 8; ++m) {
        const int src = j ^ m;
        const bool ok = real && (src < HH);
        const float* row = Ul + (ok ? src : 0) * 24;
        Ui[m] = ok ? row[0  + j] : 0.0f;
        Uf[m] = ok ? row[6  + j] : 0.0f;
        Ug[m] = ok ? row[12 + j] : 0.0f;
        Uo[m] = ok ? row[18 + j] : 0.0f;
    }

    float hl[8];           // holds ovec = ov*ec of unit (j^m); true h = ovec * r2
    float r2 = 1.0f;       // rcp of last c-softmax sum (uniform in group)
    float c = 0.0f;
    float y[10];
#pragma unroll
    for (int m = 0; m < 8; ++m) hl[m] = 0.0f;
#pragma unroll
    for (int p = 0; p < 10; ++p) y[p] = 0.0f;

    float2 wrow[5];
#pragma unroll
    for (int q = 0; q < 5; ++q) wrow[q] = *(const float2*)(w10s + jc * 10 + q * 2);

    const float* xb = xz + (size_t)b * (TT * 24) + j * 4;

    auto step = [&](const float4 z4, const int t) {
        // z = z4 + (sum_m hl[m]*U[m]) * r2   (split into two chains of 4)
        float di0 = hl[0]*Ui[0], di1 = hl[4]*Ui[4];
        float df0 = hl[0]*Uf[0], df1 = hl[4]*Uf[4];
        float dg0 = hl[0]*Ug[0], dg1 = hl[4]*Ug[4];
        float dq0 = hl[0]*Uo[0], dq1 = hl[4]*Uo[4];
#pragma unroll
        for (int m = 1; m < 4; ++m) {
            di0 = fmaf(hl[m], Ui[m], di0); di1 = fmaf(hl[m+4], Ui[m+4], di1);
            df0 = fmaf(hl[m], Uf[m], df0); df1 = fmaf(hl[m+4], Uf[m+4], df1);
            dg0 = fmaf(hl[m], Ug[m], dg0); dg1 = fmaf(hl[m+4], Ug[m+4], dg1);
            dq0 = fmaf(hl[m], Uo[m], dq0); dq1 = fmaf(hl[m+4], Uo[m+4], dq1);
        }
        const float zi = fmaf(di0 + di1, r2, z4.x);
        const float zf = fmaf(df0 + df1, r2, z4.y);
        const float zg = fmaf(dg0 + dg1, r2, z4.z);
        const float zo = fmaf(dq0 + dq1, r2, z4.w);

        const float iv = sigmoidf(zi);
        const float fv = sigmoidf(zf);
        const float ov = sigmoidf(zo);

        // g-softmax without max-subtraction (|zg| small; pads masked to 0)
        const float eg = real ? __expf(zg) : 0.0f;
        float s1 = eg;
        s1 += dppf<DPP_XOR1>(s1);
        s1 += dppf<DPP_XOR2>(s1);
        s1 += dpp_xor4(s1);
        c = fmaf(fv, c, (iv * eg) * fast_rcp(s1));

        // c-softmax (keep max for safety)
        const float cmsk = real ? c : -1e30f;
        float m2 = fmaxf(cmsk, dppf<DPP_XOR1>(cmsk));
        m2 = fmaxf(m2, dppf<DPP_XOR2>(m2));
        m2 = fmaxf(m2, dpp_xor4(m2));
        const float ec = real ? __expf(c - m2) : 0.0f;
        float s2 = ec;
        s2 += dppf<DPP_XOR1>(s2);
        s2 += dppf<DPP_XOR2>(s2);
        s2 += dpp_xor4(s2);

        // broadcast ovec = ov*ec (r2 applied at next matvec; rcp hidden under ladder)
        const float ovec = ov * ec;
        hl[0] = ovec;
        hl[1] = dppf<DPP_XOR1>(ovec);
        hl[2] = dppf<DPP_XOR2>(ovec);
        hl[3] = dppf<DPP_XOR3>(ovec);
        const float h7 = dppf<DPP_HALF>(ovec);
        hl[7] = h7;
        hl[6] = dppf<DPP_XOR1>(h7);
        hl[5] = dppf<DPP_XOR2>(h7);
        hl[4] = dppf<DPP_XOR3>(h7);
        r2 = fast_rcp(s2);
        const float hn = ovec * r2;   // actual h for this lane's unit (pads: 0)

        // prefetch next W10 row from LDS, consume current
        float2 wn[5];
        const int rn = ((t + 1) * HH + jc) * 10;
#pragma unroll
        for (int q = 0; q < 5; ++q) wn[q] = *(const float2*)(w10s + rn + q * 2);
#pragma unroll
        for (int q = 0; q < 5; ++q) {
            y[2*q]   = fmaf(hn, wrow[q].x, y[2*q]);
            y[2*q+1] = fmaf(hn, wrow[q].y, y[2*q+1]);
        }
#pragma unroll
        for (int q = 0; q < 5; ++q) wrow[q] = wn[q];
    };

    float4 A[4], B[4], C[4], D[4];
    const float* xp = xb;

#define LDBLK(Bf, dt0)                                                  \
    { _Pragma("unroll") for (int q = 0; q < 4; ++q)                     \
        Bf[q] = *(const float4*)(xp + (dt0 + q) * 24); }

    LDBLK(A, 0); LDBLK(B, 4); LDBLK(C, 8);

#pragma unroll 1
    for (int it = 0; it < 16; ++it) {
        const int t0 = it * 16;
        LDBLK(D, 12);
        step(A[0], t0 + 0);  step(A[1], t0 + 1);  step(A[2], t0 + 2);  step(A[3], t0 + 3);
        LDBLK(A, 16);   // next iter's A (last iter: dead load into valid ws memory)
        step(B[0], t0 + 4);  step(B[1], t0 + 5);  step(B[2], t0 + 6);  step(B[3], t0 + 7);
        LDBLK(B, 20);
        step(C[0], t0 + 8);  step(C[1], t0 + 9);  step(C[2], t0 + 10); step(C[3], t0 + 11);
        LDBLK(C, 24);
        step(D[0], t0 + 12); step(D[1], t0 + 13); step(D[2], t0 + 14); step(D[3], t0 + 15);
        xp += 16 * 24;
    }
#undef LDBLK

    // reduce y across the 8-lane group (pads contributed 0)
#pragma unroll
    for (int p = 0; p < 10; ++p) {
        float v = y[p];
        v += dppf<DPP_XOR1>(v);
        v += dppf<DPP_XOR2>(v);
        v += dpp_xor4(v);
        y[p] = v;
    }

    // fused dense(8): lane j emits output column j
    float o8 = bo[j];
#pragma unroll
    for (int p = 0; p < 10; ++p) o8 = fmaf(y[p] + b10[p], Wo[p * 8 + j], o8);
    out[(size_t)b * 8 + j] = o8;
}

extern "C" void kernel_launch(void* const* d_in, const int* in_sizes, int n_in,
                              void* d_out, int out_size, void* d_ws, size_t ws_size,
                              hipStream_t stream) {
    const float* x   = (const float*)d_in[0];
    const float* Wa  = (const float*)d_in[1];
    const float* ba  = (const float*)d_in[2];
    const float* Wl  = (const float*)d_in[3];
    const float* Ul  = (const float*)d_in[4];
    const float* bl  = (const float*)d_in[5];
    const float* W10 = (const float*)d_in[6];
    const float* b10 = (const float*)d_in[7];
    const float* Wo  = (const float*)d_in[8];
    const float* bo  = (const float*)d_in[9];
    float* out = (float*)d_out;
    float* xz  = (float*)d_ws;   // BB*TT*24*4 = 96 MiB (+ slack for tail prefetch)

    hipLaunchKernelGGL(k_attn_xz, dim3(BB * TT / 256), dim3(256), 0, stream,
                       x, Wa, ba, Wl, bl, xz);
    hipLaunchKernelGGL(k_scan, dim3(BB / 8), dim3(64), 0, stream,
                       xz, Ul, W10, b10, Wo, bo, out);
}